// Round 9
// baseline (10891.481 us; speedup 1.0000x reference)
//
#include <hip/hip_runtime.h>
#include <math.h>

#define PI_F 3.14159265358979323846f
typedef unsigned long long u64;

// RK stage constants: beta[k], gdt[k]=GAMMA[k]*DT, mu[k]=0.5*DT*(ALPHA[k+1]-ALPHA[k])
__constant__ float c_beta[5] = {0.0f, -0.4178904745f, -1.192151694643f,
                                -1.697784692471f, -1.514183444257f};
__constant__ float c_gdt[5]  = {1.496590219993e-4f, 3.792103129999e-4f,
                                8.229550293869e-4f, 6.994504559488e-4f,
                                1.530572479681e-4f};
__constant__ float c_mu[5]   = {7.482951099965e-5f, 1.1037096768255e-4f,
                                1.2592740288505e-4f, 1.6801318377015e-4f,
                                2.08589346626e-5f};

struct __align__(128) Line { int v; int pad[31]; };

// Batched FFT workspace: up to 4 transforms side by side.
struct SharedMem {
  float sAr[1024], sAi[1024], sBr[1024], sBi[1024];  // [4][256] ping-pong
  float twr[128], twi[128];
  float t0r[645], t0i[645], t1r[645], t1i[645];      // [129][4] tiles, stride 5
};

// ---------------------------------------------------------------------------
// Handoff data path (intra-XCD producer/consumer through the shared L2):
//   WRITE: plain store (write-through L1 -> L2 dirty write-back line, no HBM)
//   READ : relaxed agent atomic load (bypasses stale L1, hits L2, no wb/inv)
// Cross-XCD fallback stays correct via the fenced barrier (wbL2/invL2).
// ---------------------------------------------------------------------------
__device__ __forceinline__ float2 ldc(const float2* p)
{
  u64 v = __hip_atomic_load((const u64*)p, __ATOMIC_RELAXED, __HIP_MEMORY_SCOPE_AGENT);
  float2 f; __builtin_memcpy(&f, &v, 8); return f;
}
__device__ __forceinline__ void stg(float2* p, float2 f)
{
  *p = f;
}

// ---------------------------------------------------------------------------
// Fast group barrier: every block's wave 0 polls ALL n arrival lines
// directly (1/lane, relaxed). __syncthreads drains vmcnt first, so plain
// data stores are in L2 before the arrival flag.
// ---------------------------------------------------------------------------
__device__ __forceinline__ void bar_all(Line* arr, int n, int idx, int gen)
{
  __syncthreads();
  if (threadIdx.x == 0)
    __hip_atomic_store(&arr[idx].v, gen, __ATOMIC_RELAXED, __HIP_MEMORY_SCOPE_AGENT);
  if (threadIdx.x < 64) {
    bool done = false;
    while (!done) {
      bool ok = true;
      for (int w = threadIdx.x; w < n; w += 64)
        if (__hip_atomic_load(&arr[w].v, __ATOMIC_RELAXED, __HIP_MEMORY_SCOPE_AGENT) < gen)
          ok = false;
      done = __all(ok);
      if (!done) __builtin_amdgcn_s_sleep(2);
    }
    __builtin_amdgcn_sched_barrier(0);
  }
  __syncthreads();
}

// Fenced leader-based barrier (registration + cross-XCD fallback path).
__device__ __forceinline__ void bar_sync(Line* arr, Line* rel, int n, int idx,
                                         bool lead, int gen, bool fenced)
{
  const int t = threadIdx.x;
  __syncthreads();
  if (t == 0) {
    __builtin_amdgcn_s_waitcnt(0);
    __builtin_amdgcn_sched_barrier(0);
    if (fenced)
      __hip_atomic_store(&arr[idx].v, gen, __ATOMIC_RELEASE, __HIP_MEMORY_SCOPE_AGENT);
    else
      __hip_atomic_store(&arr[idx].v, gen, __ATOMIC_RELAXED, __HIP_MEMORY_SCOPE_AGENT);
  }
  if (lead && t < 64) {
    bool done = false;
    while (!done) {
      bool ok = true;
      for (int w = t; w < n; w += 64)
        if (__hip_atomic_load(&arr[w].v, __ATOMIC_RELAXED, __HIP_MEMORY_SCOPE_AGENT) < gen)
          ok = false;
      done = __all(ok);
      if (!done) __builtin_amdgcn_s_sleep(1);
    }
    __builtin_amdgcn_sched_barrier(0);
    if (fenced)
      (void)__hip_atomic_load(&arr[t & 7].v, __ATOMIC_ACQUIRE, __HIP_MEMORY_SCOPE_AGENT);
    if (t < 8) {
      if (fenced)
        __hip_atomic_store(&rel[t].v, gen, __ATOMIC_RELEASE, __HIP_MEMORY_SCOPE_AGENT);
      else
        __hip_atomic_store(&rel[t].v, gen, __ATOMIC_RELAXED, __HIP_MEMORY_SCOPE_AGENT);
    }
  }
  if (t == 0) {
    Line* f = &rel[idx & 7];
    while (__hip_atomic_load(&f->v, __ATOMIC_RELAXED, __HIP_MEMORY_SCOPE_AGENT) < gen)
      __builtin_amdgcn_s_sleep(1);
    if (fenced)
      (void)__hip_atomic_load(&f->v, __ATOMIC_ACQUIRE, __HIP_MEMORY_SCOPE_AGENT);
    __builtin_amdgcn_sched_barrier(0);
  }
  __syncthreads();
}

// ---------------------------------------------------------------------------
// Batched 256-point Stockham FFT, RADIX-4 (two verified radix-2 stages fused
// per LDS round-trip): 4 stages, 5 syncthreads (was 8 stages / 9 syncs).
// Per fused stage s in {0,2,4,6}, thread t, per transform:
//   i0 = ((t>>(s+2))<<s) + (t & ((1<<s)-1));   reads i0, i0+64, i0+128, i0+192
//   e = (t>>s)&1 selects +/- on both legs; B-leg gets extra *w[64] = -/+i;
//   p = (t>>(s+1))&1 selects the final combine with twiddle w[2*q0].
// Algebraically identical to the round-2..8 radix-2 chain (same output order,
// same normalization). Result ends in sA.
// ---------------------------------------------------------------------------
template<int B, bool INVERSE>
__device__ __forceinline__ void fftB(SharedMem& sh, int t)
{
  float *sr = sh.sAr, *si = sh.sAi, *dr = sh.sBr, *di = sh.sBi;
#pragma unroll
  for (int s = 0; s < 8; s += 2) {
    __syncthreads();
    const int m  = 1 << s;
    const int k  = t & (m - 1);
    const int e  = (t >> s) & 1;
    const int p  = (t >> (s + 1)) & 1;
    const int q0 = (t >> (s + 2)) << s;
    const int i0 = q0 + k;
    const float w1r = sh.twr[q0];
    const float w1i = INVERSE ? -sh.twi[q0] : sh.twi[q0];
    const int q2 = q0 << 1;
    const float w2r = sh.twr[q2];
    const float w2i = INVERSE ? -sh.twi[q2] : sh.twi[q2];
#pragma unroll
    for (int f = 0; f < B; ++f) {
      const int base = f * 256;
      float S0r = sr[base + i0],       S0i = si[base + i0];
      float S1r = sr[base + i0 + 128], S1i = si[base + i0 + 128];
      float S2r = sr[base + i0 + 64],  S2i = si[base + i0 + 64];
      float S3r = sr[base + i0 + 192], S3i = si[base + i0 + 192];
      float Ar, Ai, Br, Bi;
      if (e == 0) {
        Ar = S0r + S1r; Ai = S0i + S1i;
        Br = S2r + S3r; Bi = S2i + S3i;
      } else {
        float xr = S0r - S1r, xi = S0i - S1i;
        Ar = xr * w1r - xi * w1i;
        Ai = xr * w1i + xi * w1r;
        float yr = S2r - S3r, yi = S2i - S3i;
        float tr = yr * w1r - yi * w1i;
        float ti = yr * w1i + yi * w1r;
        // * w[64] = -i (forward) / +i (inverse)
        Br = INVERSE ? -ti : ti;
        Bi = INVERSE ?  tr : -tr;
      }
      float Or, Oi;
      if (p == 0) { Or = Ar + Br; Oi = Ai + Bi; }
      else {
        float xr = Ar - Br, xi = Ai - Bi;
        Or = xr * w2r - xi * w2i;
        Oi = xr * w2i + xi * w2r;
      }
      dr[base + t] = Or; di[base + t] = Oi;
    }
    float* tp;
    tp = sr; sr = dr; dr = tp;
    tp = si; si = di; di = tp;
  }
  __syncthreads();
}

// ---------------------------------------------------------------------------
// Layouts (float2). ky truncated to <=85 (dealias zeroes the rest forever).
//   u, h : [b][ky][kx]     8*129*256   (plain cached: same-block reuse)
//   G    : [f][b][ky][x]   4*8*129*256 (handoff: plain store / ldc load)
//   NL1  : [b][ky][x]      8*86*256    (handoff)
//   rec  : [r][b][ky][kx]  3*8*129*256 (handoff; r=0 slab doubles as W1)
// ---------------------------------------------------------------------------

// real-space item: 4 x-columns. 3 batched FFT passes (4v, 4g, 2fwd).
__device__ __forceinline__ void real_item4(SharedMem& sh, int t, int b, int x0,
    const float2* __restrict__ G, float2* __restrict__ NL1)
{
  for (int i = t; i < 516; i += 256) {               // fields 0,1 tiles
    int ky = i >> 2, xl = i & 3;
    float ax = 0.f, ay = 0.f, cx = 0.f, cy = 0.f;
    if (ky <= 85) {
      float2 a = ldc(&G[(((size_t)0 * 8 + b) * 129 + ky) * 256 + x0 + xl]);
      float2 c = ldc(&G[(((size_t)1 * 8 + b) * 129 + ky) * 256 + x0 + xl]);
      ax = a.x; ay = a.y; cx = c.x; cy = c.y;
    }
    sh.t0r[ky * 5 + xl] = ax; sh.t0i[ky * 5 + xl] = ay;
    sh.t1r[ky * 5 + xl] = cx; sh.t1i[ky * 5 + xl] = cy;
  }
  __syncthreads();
  const int  kk    = (t <= 128) ? t : 256 - t;
  const bool lower = (t <= 128);
#pragma unroll
  for (int xl = 0; xl < 4; ++xl) {                   // Z = Hvx + i*Hvy
    float ar = sh.t0r[kk * 5 + xl], ai = sh.t0i[kk * 5 + xl];
    float br = sh.t1r[kk * 5 + xl], bi = sh.t1i[kk * 5 + xl];
    sh.sAr[xl * 256 + t] = lower ? (ar - bi) : (ar + bi);
    sh.sAi[xl * 256 + t] = lower ? (ai + br) : (br - ai);
  }
  fftB<4, true>(sh, t);
  float vxr[4], vyr[4];
#pragma unroll
  for (int xl = 0; xl < 4; ++xl) { vxr[xl] = sh.sAr[xl * 256 + t]; vyr[xl] = sh.sAi[xl * 256 + t]; }
  for (int i = t; i < 516; i += 256) {               // fields 2,3 tiles
    int ky = i >> 2, xl = i & 3;
    float ax = 0.f, ay = 0.f, cx = 0.f, cy = 0.f;
    if (ky <= 85) {
      float2 a = ldc(&G[(((size_t)2 * 8 + b) * 129 + ky) * 256 + x0 + xl]);
      float2 c = ldc(&G[(((size_t)3 * 8 + b) * 129 + ky) * 256 + x0 + xl]);
      ax = a.x; ay = a.y; cx = c.x; cy = c.y;
    }
    sh.t0r[ky * 5 + xl] = ax; sh.t0i[ky * 5 + xl] = ay;
    sh.t1r[ky * 5 + xl] = cx; sh.t1i[ky * 5 + xl] = cy;
  }
  __syncthreads();
  float nl[4];
#pragma unroll
  for (int xl = 0; xl < 4; ++xl) {                   // Z = Hgx + i*Hgy
    float ar = sh.t0r[kk * 5 + xl], ai = sh.t0i[kk * 5 + xl];
    float br = sh.t1r[kk * 5 + xl], bi = sh.t1i[kk * 5 + xl];
    sh.sAr[xl * 256 + t] = lower ? (ar - bi) : (ar + bi);
    sh.sAi[xl * 256 + t] = lower ? (ai + br) : (br - ai);
  }
  fftB<4, true>(sh, t);
#pragma unroll
  for (int xl = 0; xl < 4; ++xl)
    nl[xl] = -(vxr[xl] * sh.sAr[xl * 256 + t] + vyr[xl] * sh.sAi[xl * 256 + t]);
  // forward rfft of 4 real rows packed into 2 complex FFTs
  sh.sAr[t]       = nl[0]; sh.sAi[t]       = nl[1];
  sh.sAr[256 + t] = nl[2]; sh.sAi[256 + t] = nl[3];
  fftB<2, false>(sh, t);
  if (t <= 85) {
    int mI = (256 - t) & 255;
#pragma unroll
    for (int p = 0; p < 2; ++p) {
      float zr = sh.sAr[p * 256 + t],  zi = sh.sAi[p * 256 + t];
      float wr = sh.sAr[p * 256 + mI], wi = sh.sAi[p * 256 + mI];
      stg(&NL1[((size_t)b * 86 + t) * 256 + x0 + 2 * p],
          make_float2(0.5f * (zr + wr), 0.5f * (zi - wi)));
      stg(&NL1[((size_t)b * 86 + t) * 256 + x0 + 2 * p + 1],
          make_float2(0.5f * (zi + wi), 0.5f * (wr - zr)));
    }
  }
  __syncthreads();   // protect cross-lane sA reads before next item's staging
}

// spectral item: 2 ky rows (ky0, ky0+1; both <86). fwd batch-2 + 2x inverse batch-4.
__device__ __forceinline__ void spectral_item2(SharedMem& sh, int t, int b, int ky0,
    const float2* __restrict__ NL1, float2* __restrict__ u, float2* __restrict__ h,
    float2* __restrict__ G, float2* __restrict__ rec,
    float beta, float gdt, float mu, bool doUpdate, int recIdx)
{
  const int jx = (t < 128) ? t : t - 256;
  const float fjx = (float)jx;
  float ur[2], ui[2];
#pragma unroll
  for (int f = 0; f < 2; ++f) {
    float2 uu = u[((size_t)b * 129 + ky0 + f) * 256 + t];
    ur[f] = uu.x; ui[f] = uu.y;
  }

  if (doUpdate) {
#pragma unroll
    for (int f = 0; f < 2; ++f) {
      float2 nv = ldc(&NL1[((size_t)b * 86 + ky0 + f) * 256 + t]);
      sh.sAr[f * 256 + t] = nv.x; sh.sAi[f * 256 + t] = nv.y;
    }
    fftB<2, false>(sh, t);
#pragma unroll
    for (int f = 0; f < 2; ++f) {
      const int ky = ky0 + f;
      const size_t row = ((size_t)b * 129 + ky) * 256;
      float advr = 0.f, advi = 0.f;
      if (t < 85 || t >= 171) { advr = sh.sAr[f * 256 + t]; advi = sh.sAi[f * 256 + t]; }
      if (t == 0 && ky == 4) {                       // forcing f_hat
        float s_, c_;
        __sincosf(PI_F / 64.0f, &s_, &c_);
        advr -= 131072.0f * c_;
        advi -= 131072.0f * s_;
      }
      float hr = advr, hi = advi;
      if (beta != 0.0f) {
        float2 hh = h[row + t];
        hr += beta * hh.x; hi += beta * hh.y;
      }
      const float k2   = (float)(jx * jx + ky * ky);
      const float lin  = -0.001f * k2 - 0.1f;
      const float anum = 1.0f + mu * lin;
      const float invd = 1.0f / (1.0f - mu * lin);
      ur[f] = (ur[f] * anum + gdt * hr) * invd;
      ui[f] = (ui[f] * anum + gdt * hi) * invd;
      u[row + t] = make_float2(ur[f], ui[f]);
      h[row + t] = make_float2(hr, hi);
      if (recIdx >= 0)
        stg(&rec[((size_t)recIdx * 8 + b) * (129 * 256) + (size_t)ky * 256 + t],
            make_float2(ur[f], ui[f]));
    }
  }

  const float NRM = 1.0f / 65536.0f;
#pragma unroll
  for (int f = 0; f < 2; ++f) {                      // inverse: 4 fields of row f
    const int ky = ky0 + f;
    const float k2 = (float)(jx * jx + ky * ky);
    const float inv_lapnz = (k2 == 0.0f) ? 1.0f : (-1.0f / k2);
    const float urN = ur[f] * NRM, uiN = ui[f] * NRM;
    const float psr = -urN * inv_lapnz, psi_ = -uiN * inv_lapnz;
    const float fjy = (float)ky;
    sh.sAr[0 * 256 + t] = -fjy * psi_; sh.sAi[0 * 256 + t] =  fjy * psr;  // vx
    sh.sAr[1 * 256 + t] =  fjx * psi_; sh.sAi[1 * 256 + t] = -fjx * psr;  // vy
    sh.sAr[2 * 256 + t] = -fjx * uiN;  sh.sAi[2 * 256 + t] =  fjx * urN;  // gx
    sh.sAr[3 * 256 + t] = -fjy * uiN;  sh.sAi[3 * 256 + t] =  fjy * urN;  // gy
    fftB<4, true>(sh, t);
#pragma unroll
    for (int fd = 0; fd < 4; ++fd)
      stg(&G[(((size_t)fd * 8 + b) * 129 + ky) * 256 + t],
          make_float2(sh.sAr[fd * 256 + t], sh.sAi[fd * 256 + t]));
  }
}

// ---------------------------------------------------------------------------
// Persistent kernel. Blocks self-organize into 8 per-XCD groups (HW_REG_XCC_ID);
// group g serves batch g. Fast path: all-poll flag barriers + L2-resident
// handoff. Fallback: blockIdx grouping with fenced leader barriers.
// ---------------------------------------------------------------------------
__global__ __launch_bounds__(256, 4) void k_persist(
    const float* __restrict__ vort, float* __restrict__ out,
    float2* __restrict__ u, float2* __restrict__ h,
    float2* __restrict__ G, float2* __restrict__ NL1, float2* __restrict__ rec,
    Line* __restrict__ bar)
{
  const int t   = threadIdx.x;
  const int blk = blockIdx.x;
  const int NBg = gridDim.x;

  Line* arrGrid = bar;                    // 1024 lines
  Line* relGrid = bar + 1024;             // 8
  Line* arrGrpA = bar + 1032;             // 8 * 256
  Line* relGrpA = bar + 1032 + 2048;      // 8 * 8
  Line* regL    = bar + 1032 + 2048 + 64; // 16: per-XCD counters

  __shared__ SharedMem sh;
  __shared__ int s_x, s_wi;

  if (t < 128) {
    float s_, c_;
    __sincosf(-(2.0f * PI_F / 256.0f) * (float)t, &s_, &c_);
    sh.twr[t] = c_; sh.twi[t] = s_;
  }

  // ---- registration: claim a worker slot on this block's physical XCD ----
  if (t == 0) {
    int x;
    asm volatile("s_getreg_b32 %0, hwreg(HW_REG_XCC_ID)" : "=s"(x));
    x &= 15;
    s_x  = x;
    s_wi = atomicAdd(&regL[x].v, 1);
  }
  __syncthreads();

  int gen = 0;
  bar_sync(arrGrid, relGrid, NBg, blk, blk == 0, ++gen, true);  // fenced grid bar

  int tot = 0, mn = 1 << 30, mx = 0;
  for (int i = 0; i < 8; ++i) {
    int c = regL[i].v;
    tot += c; mn = min(mn, c); mx = max(mx, c);
  }
  const bool fast = (tot == NBg) && (mn > 0) && (mx <= 256);
  int g, wi, nW;
  if (fast) { g = s_x;     wi = s_wi;     nW = regL[g].v; }
  else      { g = blk & 7; wi = blk >> 3; nW = NBg >> 3;  }
  Line* arr = arrGrpA + g * 256;
  Line* rel = relGrpA + g * 8;
  const bool lead = (wi == 0);

#define GBAR() do { ++gen; if (fast) bar_all(arr, nW, wi, gen); \
                    else bar_sync(arr, rel, nW, wi, lead, gen, true); } while (0)

  // ---- init: rfft along y, 4 x-rows/item packed into 2 complex FFTs ----
  float2* W1 = rec + (size_t)g * (129 * 256);
  for (int w = wi; w < 64; w += nW) {
    const int x0 = w * 4;
#pragma unroll
    for (int p = 0; p < 2; ++p) {
      sh.sAr[p * 256 + t] = vort[((size_t)g * 256 + x0 + 2 * p) * 256 + t];
      sh.sAi[p * 256 + t] = vort[((size_t)g * 256 + x0 + 2 * p + 1) * 256 + t];
    }
    fftB<2, false>(sh, t);
    if (t < 129) {
      int mI = (256 - t) & 255;
#pragma unroll
      for (int p = 0; p < 2; ++p) {
        float zr = sh.sAr[p * 256 + t],  zi = sh.sAi[p * 256 + t];
        float wr = sh.sAr[p * 256 + mI], wi2 = sh.sAi[p * 256 + mI];
        stg(&W1[(size_t)t * 256 + x0 + 2 * p],
            make_float2(0.5f * (zr + wr), 0.5f * (zi - wi2)));
        stg(&W1[(size_t)t * 256 + x0 + 2 * p + 1],
            make_float2(0.5f * (zi + wi2), 0.5f * (wr - zr)));
      }
    }
    __syncthreads();
  }
  GBAR();

  // ---- init: col FFT (W1 -> u) then prepare G; same ky pairs per block ----
  for (int w = wi; w < 43; w += nW) {
    const int ky0 = w * 2;
#pragma unroll
    for (int f = 0; f < 2; ++f) {
      float2 v = ldc(&W1[(size_t)(ky0 + f) * 256 + t]);
      sh.sAr[f * 256 + t] = v.x; sh.sAi[f * 256 + t] = v.y;
    }
    fftB<2, false>(sh, t);
#pragma unroll
    for (int f = 0; f < 2; ++f)
      u[((size_t)g * 129 + ky0 + f) * 256 + t] =
        make_float2(sh.sAr[f * 256 + t], sh.sAi[f * 256 + t]);
  }
  for (int w = wi; w < 43; w += nW)
    spectral_item2(sh, t, g, w * 2, NL1, u, h, G, rec, 0.f, 0.f, 0.f, false, -1);

  // ---- main loop: 90 steps x 5 RK stages ----
  for (int step = 1; step <= 90; ++step) {
    for (int k = 0; k < 5; ++k) {
      GBAR();
      for (int w = wi; w < 64; w += nW)
        real_item4(sh, t, g, w * 4, G, NL1);
      GBAR();
      const int recIdx = (k == 4 && step % 30 == 0) ? (step / 30 - 1) : -1;
      for (int w = wi; w < 43; w += nW)
        spectral_item2(sh, t, g, w * 2, NL1, u, h, G, rec,
                       c_beta[k], c_gdt[k], c_mu[k], true, recIdx);
    }
  }
  GBAR();

  // ---- final: inverse col FFT of records (258 rows, 2 per item) ----
  for (int w = wi; w < 129; w += nW) {
#pragma unroll
    for (int j = 0; j < 2; ++j) {
      int idx = w * 2 + j, r = idx / 86, ky = idx % 86;
      float2 v = ldc(&rec[(((size_t)r * 8 + g) * 129 + ky) * 256 + t]);
      sh.sAr[j * 256 + t] = v.x; sh.sAi[j * 256 + t] = v.y;
    }
    fftB<2, true>(sh, t);
#pragma unroll
    for (int j = 0; j < 2; ++j) {
      int idx = w * 2 + j, r = idx / 86, ky = idx % 86;
      stg(&G[(((size_t)r * 8 + g) * 129 + ky) * 256 + t],
          make_float2(sh.sAr[j * 256 + t], sh.sAi[j * 256 + t]));
    }
  }
  GBAR();

  // ---- final: paired hermitian inverse row FFT -> out (4 cols/item) ----
  const float NRM = 1.0f / 65536.0f;
  for (int w = wi; w < 192; w += nW) {
    const int r = w / 64, xh = w % 64, x0 = xh * 4;
    for (int i = t; i < 516; i += 256) {
      int ky = i >> 2, xl = i & 3;
      float ax = 0.f, ay = 0.f;
      if (ky <= 85) {
        float2 a = ldc(&G[(((size_t)r * 8 + g) * 129 + ky) * 256 + x0 + xl]);
        ax = a.x; ay = a.y;
      }
      sh.t0r[ky * 5 + xl] = ax; sh.t0i[ky * 5 + xl] = ay;
    }
    __syncthreads();
    const int  kk    = (t <= 128) ? t : 256 - t;
    const bool lower = (t <= 128);
#pragma unroll
    for (int f = 0; f < 2; ++f) {
      float ar = sh.t0r[kk * 5 + 2 * f],     ai = sh.t0i[kk * 5 + 2 * f];
      float br = sh.t0r[kk * 5 + 2 * f + 1], bi = sh.t0i[kk * 5 + 2 * f + 1];
      sh.sAr[f * 256 + t] = lower ? (ar - bi) : (ar + bi);
      sh.sAi[f * 256 + t] = lower ? (ai + br) : (br - ai);
    }
    fftB<2, true>(sh, t);
#pragma unroll
    for (int f = 0; f < 2; ++f) {
      out[((((size_t)r * 8 + g) * 256) + x0 + 2 * f) * 256 + t]     = sh.sAr[f * 256 + t] * NRM;
      out[((((size_t)r * 8 + g) * 256) + x0 + 2 * f + 1) * 256 + t] = sh.sAi[f * 256 + t] * NRM;
    }
    __syncthreads();
  }
#undef GBAR
}

// ---------------------------------------------------------------------------
extern "C" void kernel_launch(void* const* d_in, const int* in_sizes, int n_in,
                              void* d_out, int out_size, void* d_ws, size_t ws_size,
                              hipStream_t stream)
{
  const float* vort = (const float*)d_in[0];
  float* out = (float*)d_out;

  float2* base = (float2*)d_ws;
  float2* u    = base;                 // 8*129*256   = 264192
  float2* h    = u + 264192;           // 264192
  float2* G    = h + 264192;           // 4*8*129*256 = 1056768
  float2* NL1  = G + 1056768;          // 8*86*256    = 176128
  float2* rec  = NL1 + 176128;         // 3*8*129*256 = 792576
  Line*   bar  = (Line*)(rec + 792576);
  const int nLines = 1024 + 8 + 2048 + 64 + 16;   // 3160 lines

  hipMemsetAsync(bar, 0, (size_t)nLines * sizeof(Line), stream);

  int maxPerCU = 0;
  hipOccupancyMaxActiveBlocksPerMultiprocessor(&maxPerCU, k_persist, 256, 0);
  int NBg = maxPerCU * 256;            // 256 CUs on MI355X
  if (NBg <= 0)  NBg = 512;
  if (NBg > 512) NBg = 512;            // ~64 blocks/XCD: all busy in real phase
  NBg &= ~63;
  if (NBg < 64)  NBg = 64;

  void* args[] = {(void*)&vort, (void*)&out, (void*)&u, (void*)&h,
                  (void*)&G, (void*)&NL1, (void*)&rec, (void*)&bar};
  hipError_t e = hipLaunchCooperativeKernel(k_persist, dim3(NBg), dim3(256),
                                            args, 0, stream);
  if (e != hipSuccess) {
    hipLaunchKernelGGL(k_persist, dim3(NBg), dim3(256), 0, stream,
                       vort, out, u, h, G, NL1, rec, bar);
  }
}

// Round 10
// 7358.626 us; speedup vs baseline: 1.4801x; 1.4801x over previous
//
#include <hip/hip_runtime.h>
#include <math.h>

#define PI_F 3.14159265358979323846f
typedef unsigned long long u64;

// RK stage constants: beta[k], gdt[k]=GAMMA[k]*DT, mu[k]=0.5*DT*(ALPHA[k+1]-ALPHA[k])
__constant__ float c_beta[5] = {0.0f, -0.4178904745f, -1.192151694643f,
                                -1.697784692471f, -1.514183444257f};
__constant__ float c_gdt[5]  = {1.496590219993e-4f, 3.792103129999e-4f,
                                8.229550293869e-4f, 6.994504559488e-4f,
                                1.530572479681e-4f};
__constant__ float c_mu[5]   = {7.482951099965e-5f, 1.1037096768255e-4f,
                                1.2592740288505e-4f, 1.6801318377015e-4f,
                                2.08589346626e-5f};

struct __align__(128) Line { int v; int pad[31]; };

struct SharedMem {
  float sAr[1024], sAi[1024], sBr[1024], sBi[1024];  // [4][256] ping-pong
  float twr[128], twi[128];
  float t0r[430], t0i[430], t1r[430], t1i[430];      // [86][4] tiles, stride 5
};

// ---------------------------------------------------------------------------
// Handoff: plain stores (L2-resident, round 8) + relaxed agent loads (L1 bypass)
// ---------------------------------------------------------------------------
__device__ __forceinline__ float2 ldc(const float2* p)
{
  u64 v = __hip_atomic_load((const u64*)p, __ATOMIC_RELAXED, __HIP_MEMORY_SCOPE_AGENT);
  float2 f; __builtin_memcpy(&f, &v, 8); return f;
}
__device__ __forceinline__ void stg(float2* p, float2 f) { *p = f; }

// ---------------------------------------------------------------------------
// Fast group barrier (all-poll) + fenced fallback barrier — as round 8.
// ---------------------------------------------------------------------------
__device__ __forceinline__ void bar_all(Line* arr, int n, int idx, int gen)
{
  __syncthreads();
  if (threadIdx.x == 0)
    __hip_atomic_store(&arr[idx].v, gen, __ATOMIC_RELAXED, __HIP_MEMORY_SCOPE_AGENT);
  if (threadIdx.x < 64) {
    bool done = false;
    while (!done) {
      bool ok = true;
      for (int w = threadIdx.x; w < n; w += 64)
        if (__hip_atomic_load(&arr[w].v, __ATOMIC_RELAXED, __HIP_MEMORY_SCOPE_AGENT) < gen)
          ok = false;
      done = __all(ok);
      if (!done) __builtin_amdgcn_s_sleep(2);
    }
    __builtin_amdgcn_sched_barrier(0);
  }
  __syncthreads();
}

__device__ __forceinline__ void bar_sync(Line* arr, Line* rel, int n, int idx,
                                         bool lead, int gen, bool fenced)
{
  const int t = threadIdx.x;
  __syncthreads();
  if (t == 0) {
    __builtin_amdgcn_s_waitcnt(0);
    __builtin_amdgcn_sched_barrier(0);
    if (fenced)
      __hip_atomic_store(&arr[idx].v, gen, __ATOMIC_RELEASE, __HIP_MEMORY_SCOPE_AGENT);
    else
      __hip_atomic_store(&arr[idx].v, gen, __ATOMIC_RELAXED, __HIP_MEMORY_SCOPE_AGENT);
  }
  if (lead && t < 64) {
    bool done = false;
    while (!done) {
      bool ok = true;
      for (int w = t; w < n; w += 64)
        if (__hip_atomic_load(&arr[w].v, __ATOMIC_RELAXED, __HIP_MEMORY_SCOPE_AGENT) < gen)
          ok = false;
      done = __all(ok);
      if (!done) __builtin_amdgcn_s_sleep(1);
    }
    __builtin_amdgcn_sched_barrier(0);
    if (fenced)
      (void)__hip_atomic_load(&arr[t & 7].v, __ATOMIC_ACQUIRE, __HIP_MEMORY_SCOPE_AGENT);
    if (t < 8) {
      if (fenced)
        __hip_atomic_store(&rel[t].v, gen, __ATOMIC_RELEASE, __HIP_MEMORY_SCOPE_AGENT);
      else
        __hip_atomic_store(&rel[t].v, gen, __ATOMIC_RELAXED, __HIP_MEMORY_SCOPE_AGENT);
    }
  }
  if (t == 0) {
    Line* f = &rel[idx & 7];
    while (__hip_atomic_load(&f->v, __ATOMIC_RELAXED, __HIP_MEMORY_SCOPE_AGENT) < gen)
      __builtin_amdgcn_s_sleep(1);
    if (fenced)
      (void)__hip_atomic_load(&f->v, __ATOMIC_ACQUIRE, __HIP_MEMORY_SCOPE_AGENT);
    __builtin_amdgcn_sched_barrier(0);
  }
  __syncthreads();
}

// ---------------------------------------------------------------------------
// LDS batched radix-4 Stockham FFT (verified, round 9) — used in init/final.
// ---------------------------------------------------------------------------
template<int B, bool INVERSE>
__device__ __forceinline__ void fftB(SharedMem& sh, int t)
{
  float *sr = sh.sAr, *si = sh.sAi, *dr = sh.sBr, *di = sh.sBi;
#pragma unroll
  for (int s = 0; s < 8; s += 2) {
    __syncthreads();
    const int m  = 1 << s;
    const int k  = t & (m - 1);
    const int e  = (t >> s) & 1;
    const int p  = (t >> (s + 1)) & 1;
    const int q0 = (t >> (s + 2)) << s;
    const int i0 = q0 + k;
    const float w1r = sh.twr[q0];
    const float w1i = INVERSE ? -sh.twi[q0] : sh.twi[q0];
    const float w2r = sh.twr[q0 << 1];
    const float w2i = INVERSE ? -sh.twi[q0 << 1] : sh.twi[q0 << 1];
#pragma unroll
    for (int f = 0; f < B; ++f) {
      const int base = f * 256;
      float S0r = sr[base + i0],       S0i = si[base + i0];
      float S1r = sr[base + i0 + 128], S1i = si[base + i0 + 128];
      float S2r = sr[base + i0 + 64],  S2i = si[base + i0 + 64];
      float S3r = sr[base + i0 + 192], S3i = si[base + i0 + 192];
      float Ar, Ai, Br, Bi;
      if (e == 0) { Ar = S0r + S1r; Ai = S0i + S1i; Br = S2r + S3r; Bi = S2i + S3i; }
      else {
        float xr = S0r - S1r, xi = S0i - S1i;
        Ar = xr * w1r - xi * w1i; Ai = xr * w1i + xi * w1r;
        float yr = S2r - S3r, yi = S2i - S3i;
        float tr = yr * w1r - yi * w1i, ti = yr * w1i + yi * w1r;
        Br = INVERSE ? -ti : ti; Bi = INVERSE ? tr : -tr;
      }
      float Or, Oi;
      if (p == 0) { Or = Ar + Br; Oi = Ai + Bi; }
      else {
        float xr = Ar - Br, xi = Ai - Bi;
        Or = xr * w2r - xi * w2i; Oi = xr * w2i + xi * w2r;
      }
      dr[base + t] = Or; di[base + t] = Oi;
    }
    float* tp;
    tp = sr; sr = dr; dr = tp;
    tp = si; si = di; di = tp;
  }
  __syncthreads();
}

// ---------------------------------------------------------------------------
// REGISTER radix-4 Stockham FFT: 64 threads per transform, 4 points/thread
// (positions tt+64j), B transforms (f = t>>6 < B active). Same algebra /
// twiddles / output order as fftB; LDS only for the 3 inter-stage exchanges.
// Caller fills v[j] = point at position tt+64j; result returned the same way.
// ---------------------------------------------------------------------------
template<int B, bool INVERSE>
__device__ __forceinline__ void fft_reg(SharedMem& sh, int t,
                                        float (&vr)[4], float (&vi)[4])
{
  const int f  = t >> 6;
  const int tt = t & 63;
  const bool act = (f < B);
  __syncthreads();                       // protect first exchange buffer (WAR)
#pragma unroll
  for (int s4 = 0; s4 < 4; ++s4) {
    const int s = s4 * 2;
    float o_r[4], o_i[4];
    int pos0 = 0;
    if (act) {
      const int k  = tt & ((1 << s) - 1);
      const int q0 = tt - k;
      const float w1r = sh.twr[q0];
      const float w1i = INVERSE ? -sh.twi[q0] : sh.twi[q0];
      const float w2r = sh.twr[q0 << 1];
      const float w2i = INVERSE ? -sh.twi[q0 << 1] : sh.twi[q0 << 1];
      // S0=v[0](+0)  S2=v[1](+64)  S1=v[2](+128)  S3=v[3](+192)
      float Ar  = vr[0] + vr[2], Ai  = vi[0] + vi[2];
      float dr_ = vr[0] - vr[2], di_ = vi[0] - vi[2];
      float Atr = dr_ * w1r - di_ * w1i, Ati = dr_ * w1i + di_ * w1r;
      float Br  = vr[1] + vr[3], Bi  = vi[1] + vi[3];
      float er_ = vr[1] - vr[3], ei_ = vi[1] - vi[3];
      float tr_ = er_ * w1r - ei_ * w1i, ti_ = er_ * w1i + ei_ * w1r;
      float Btr = INVERSE ? -ti_ : ti_;
      float Bti = INVERSE ?  tr_ : -tr_;
      o_r[0] = Ar + Br;   o_i[0] = Ai + Bi;
      o_r[1] = Atr + Btr; o_i[1] = Ati + Bti;
      float c0r = Ar - Br,   c0i = Ai - Bi;
      float c1r = Atr - Btr, c1i = Ati - Bti;
      o_r[2] = c0r * w2r - c0i * w2i; o_i[2] = c0r * w2i + c0i * w2r;
      o_r[3] = c1r * w2r - c1i * w2i; o_i[3] = c1r * w2i + c1i * w2r;
      pos0 = ((tt >> s) << (s + 2)) + k;
    }
    if (s4 < 3) {
      float* br_ = (s4 & 1) ? sh.sBr : sh.sAr;
      float* bi_ = (s4 & 1) ? sh.sBi : sh.sAi;
      if (act) {
#pragma unroll
        for (int m = 0; m < 4; ++m) {
          br_[f * 256 + pos0 + (m << s)] = o_r[m];
          bi_[f * 256 + pos0 + (m << s)] = o_i[m];
        }
      }
      __syncthreads();
      if (act) {
#pragma unroll
        for (int j = 0; j < 4; ++j) {
          vr[j] = br_[f * 256 + tt + 64 * j];
          vi[j] = bi_[f * 256 + tt + 64 * j];
        }
      }
    } else if (act) {
#pragma unroll
      for (int j = 0; j < 4; ++j) { vr[j] = o_r[j]; vi[j] = o_i[j]; }
    }
  }
}

// ---------------------------------------------------------------------------
// Layouts (float2). ky truncated to <=85.
//   u, h : [b][ky][kx]     8*129*256   (plain; same-block producer/consumer)
//   G    : [f][b][ky][x]   4*8*129*256 (handoff)
//   NL1  : [b][ky][x]      8*86*256    (handoff)
//   rec  : [r][b][ky][kx]  3*8*129*256 (handoff; r=0 slab doubles as W1)
// ---------------------------------------------------------------------------

__device__ __forceinline__ void stage_tiles(SharedMem& sh, int t, int b, int x0,
    int q0_, int q1_, const float2* __restrict__ G)
{
  for (int i = t; i < 344; i += 256) {
    int ky = i >> 2, xl = i & 3;
    float2 a = ldc(&G[(((size_t)q0_ * 8 + b) * 129 + ky) * 256 + x0 + xl]);
    float2 c = ldc(&G[(((size_t)q1_ * 8 + b) * 129 + ky) * 256 + x0 + xl]);
    sh.t0r[ky * 5 + xl] = a.x; sh.t0i[ky * 5 + xl] = a.y;
    sh.t1r[ky * 5 + xl] = c.x; sh.t1i[ky * 5 + xl] = c.y;
  }
}

// hermitian-extended input for point n = tt+64j of column f: Z = H0 + i*H1
__device__ __forceinline__ void build_Z(SharedMem& sh, int f, int tt,
                                        float (&zr)[4], float (&zi)[4])
{
#pragma unroll
  for (int j = 0; j < 4; ++j) {
    int n = tt + 64 * j;
    bool low = (n <= 128);
    int kk = low ? n : 256 - n;
    float ar = 0.f, ai = 0.f, br = 0.f, bi = 0.f;
    if (kk <= 85) {
      ar = sh.t0r[kk * 5 + f]; ai = sh.t0i[kk * 5 + f];
      br = sh.t1r[kk * 5 + f]; bi = sh.t1i[kk * 5 + f];
    }
    zr[j] = low ? (ar - bi) : (ar + bi);
    zi[j] = low ? (ai + br) : (br - ai);
  }
}

// real-space item: 4 x-columns, register FFTs.
__device__ __forceinline__ void real_item4_reg(SharedMem& sh, int t, int b, int x0,
    const float2* __restrict__ G, float2* __restrict__ NL1)
{
  const int f = t >> 6, tt = t & 63;
  __syncthreads();                               // tiles WAR vs previous item
  stage_tiles(sh, t, b, x0, 0, 1, G);
  __syncthreads();
  float zr[4], zi[4];
  build_Z(sh, f, tt, zr, zi);                    // Z = Hvx + i*Hvy
  fft_reg<4, true>(sh, t, zr, zi);
  float vx[4], vy[4];
#pragma unroll
  for (int j = 0; j < 4; ++j) { vx[j] = zr[j]; vy[j] = zi[j]; }
  // tiles 2,3 (tile reads for v all happened before fft entry sync -> safe)
  stage_tiles(sh, t, b, x0, 2, 3, G);
  __syncthreads();
  build_Z(sh, f, tt, zr, zi);                    // Z = Hgx + i*Hgy
  fft_reg<4, true>(sh, t, zr, zi);
  float nl[4];
#pragma unroll
  for (int j = 0; j < 4; ++j) nl[j] = -(vx[j] * zr[j] + vy[j] * zi[j]);
  // stage nl into sAr[f][n] for the packed forward transform
  __syncthreads();                               // sA WAR vs g-pass exchange reads
#pragma unroll
  for (int j = 0; j < 4; ++j) sh.sAr[f * 256 + tt + 64 * j] = nl[j];
  __syncthreads();
  float wr2[4], wi2[4];
  if (f < 2) {
#pragma unroll
    for (int j = 0; j < 4; ++j) {
      wr2[j] = sh.sAr[(2 * f) * 256 + tt + 64 * j];
      wi2[j] = sh.sAr[(2 * f + 1) * 256 + tt + 64 * j];
    }
  }
  fft_reg<2, false>(sh, t, wr2, wi2);
  if (f < 2) {
#pragma unroll
    for (int j = 0; j < 4; ++j) {
      sh.sBr[f * 256 + tt + 64 * j] = wr2[j];
      sh.sBi[f * 256 + tt + 64 * j] = wi2[j];
    }
  }
  __syncthreads();
  if (t <= 85) {                                 // hermitian extraction -> NL1
    int mI = (256 - t) & 255;
#pragma unroll
    for (int p = 0; p < 2; ++p) {
      float zr_ = sh.sBr[p * 256 + t],  zi_ = sh.sBi[p * 256 + t];
      float wr_ = sh.sBr[p * 256 + mI], wi_ = sh.sBi[p * 256 + mI];
      stg(&NL1[((size_t)b * 86 + t) * 256 + x0 + 2 * p],
          make_float2(0.5f * (zr_ + wr_), 0.5f * (zi_ - wi_)));
      stg(&NL1[((size_t)b * 86 + t) * 256 + x0 + 2 * p + 1],
          make_float2(0.5f * (zi_ + wi_), 0.5f * (wr_ - zr_)));
    }
  }
}

// spectral item: 4 ky rows (ky0..ky0+3; rows >=86 are harmless garbage lanes).
__device__ __forceinline__ void spectral_item4_reg(SharedMem& sh, int t, int b, int ky0,
    const float2* __restrict__ NL1, float2* __restrict__ u, float2* __restrict__ h,
    float2* __restrict__ G, float2* __restrict__ rec,
    float beta, float gdt, float mu, bool doUpdate, int recIdx)
{
  const int f = t >> 6, tt = t & 63;
  const int ky  = ky0 + f;                       // may be 86/87: outputs unread
  const int kyc = (ky > 85) ? 85 : ky;           // clamp NL1 addressing
  const size_t urow = ((size_t)b * 129 + ky) * 256;
  float ur_[4], ui_[4];
#pragma unroll
  for (int j = 0; j < 4; ++j) {
    float2 uu = u[urow + tt + 64 * j];
    ur_[j] = uu.x; ui_[j] = uu.y;
  }

  if (doUpdate) {
    float ar[4], ai[4];
#pragma unroll
    for (int j = 0; j < 4; ++j) {
      float2 nv = ldc(&NL1[((size_t)b * 86 + kyc) * 256 + tt + 64 * j]);
      ar[j] = nv.x; ai[j] = nv.y;
    }
    fft_reg<4, false>(sh, t, ar, ai);
#pragma unroll
    for (int j = 0; j < 4; ++j) {
      const int kx = tt + 64 * j;
      const bool keep = (kx < 85) || (kx >= 171);
      float advr = keep ? ar[j] : 0.f;
      float advi = keep ? ai[j] : 0.f;
      if (kx == 0 && ky == 4) {                  // forcing f_hat
        float s_, c_;
        __sincosf(PI_F / 64.0f, &s_, &c_);
        advr -= 131072.0f * c_;
        advi -= 131072.0f * s_;
      }
      float hr = advr, hi = advi;
      if (beta != 0.0f) {
        float2 hh = h[urow + kx];
        hr += beta * hh.x; hi += beta * hh.y;
      }
      const int jx = (kx < 128) ? kx : kx - 256;
      const float k2   = (float)(jx * jx + ky * ky);
      const float lin  = -0.001f * k2 - 0.1f;
      const float anum = 1.0f + mu * lin;
      const float invd = 1.0f / (1.0f - mu * lin);
      ur_[j] = (ur_[j] * anum + gdt * hr) * invd;
      ui_[j] = (ui_[j] * anum + gdt * hi) * invd;
      u[urow + kx] = make_float2(ur_[j], ui_[j]);
      h[urow + kx] = make_float2(hr, hi);
      if (recIdx >= 0)
        stg(&rec[((size_t)recIdx * 8 + b) * (129 * 256) + (size_t)ky * 256 + kx],
            make_float2(ur_[j], ui_[j]));
    }
  }

  const float NRM = 1.0f / 65536.0f;
  const float fjy = (float)ky;
#pragma unroll
  for (int q = 0; q < 4; ++q) {                  // 4 field inverse FFTs
    float xr[4], xi[4];
#pragma unroll
    for (int j = 0; j < 4; ++j) {
      const int kx = tt + 64 * j;
      const int jx = (kx < 128) ? kx : kx - 256;
      const float fjx = (float)jx;
      const float k2 = (float)(jx * jx + ky * ky);
      const float inv_lapnz = (k2 == 0.0f) ? 1.0f : (-1.0f / k2);
      const float urN = ur_[j] * NRM, uiN = ui_[j] * NRM;
      const float psr = -urN * inv_lapnz, psi_ = -uiN * inv_lapnz;
      if      (q == 0) { xr[j] = -fjy * psi_; xi[j] =  fjy * psr; }   // vx
      else if (q == 1) { xr[j] =  fjx * psi_; xi[j] = -fjx * psr; }   // vy
      else if (q == 2) { xr[j] = -fjx * uiN;  xi[j] =  fjx * urN; }   // gx
      else             { xr[j] = -fjy * uiN;  xi[j] =  fjy * urN; }   // gy
    }
    fft_reg<4, true>(sh, t, xr, xi);
#pragma unroll
    for (int j = 0; j < 4; ++j)
      stg(&G[(((size_t)q * 8 + b) * 129 + ky) * 256 + tt + 64 * j],
          make_float2(xr[j], xi[j]));
  }
}

// ---------------------------------------------------------------------------
// Persistent kernel: per-XCD groups, fast flag barriers, L2-resident handoff.
// ---------------------------------------------------------------------------
__global__ __launch_bounds__(256, 2) void k_persist(
    const float* __restrict__ vort, float* __restrict__ out,
    float2* __restrict__ u, float2* __restrict__ h,
    float2* __restrict__ G, float2* __restrict__ NL1, float2* __restrict__ rec,
    Line* __restrict__ bar)
{
  const int t   = threadIdx.x;
  const int blk = blockIdx.x;
  const int NBg = gridDim.x;

  Line* arrGrid = bar;                    // 1024 lines
  Line* relGrid = bar + 1024;             // 8
  Line* arrGrpA = bar + 1032;             // 8 * 256
  Line* relGrpA = bar + 1032 + 2048;      // 8 * 8
  Line* regL    = bar + 1032 + 2048 + 64; // 16: per-XCD counters

  __shared__ SharedMem sh;
  __shared__ int s_x, s_wi;

  if (t < 128) {
    float s_, c_;
    __sincosf(-(2.0f * PI_F / 256.0f) * (float)t, &s_, &c_);
    sh.twr[t] = c_; sh.twi[t] = s_;
  }

  if (t == 0) {
    int x;
    asm volatile("s_getreg_b32 %0, hwreg(HW_REG_XCC_ID)" : "=s"(x));
    x &= 15;
    s_x  = x;
    s_wi = atomicAdd(&regL[x].v, 1);
  }
  __syncthreads();

  int gen = 0;
  bar_sync(arrGrid, relGrid, NBg, blk, blk == 0, ++gen, true);  // fenced grid bar

  int tot = 0, mn = 1 << 30, mx = 0;
  for (int i = 0; i < 8; ++i) {
    int c = regL[i].v;
    tot += c; mn = min(mn, c); mx = max(mx, c);
  }
  const bool fast = (tot == NBg) && (mn > 0) && (mx <= 256);
  int g, wi, nW;
  if (fast) { g = s_x;     wi = s_wi;     nW = regL[g].v; }
  else      { g = blk & 7; wi = blk >> 3; nW = NBg >> 3;  }
  Line* arr = arrGrpA + g * 256;
  Line* rel = relGrpA + g * 8;
  const bool lead = (wi == 0);

#define GBAR() do { ++gen; if (fast) bar_all(arr, nW, wi, gen); \
                    else bar_sync(arr, rel, nW, wi, lead, gen, true); } while (0)

  // ---- init: rfft along y, 4 x-rows/item packed into 2 complex FFTs ----
  float2* W1 = rec + (size_t)g * (129 * 256);
  for (int w = wi; w < 64; w += nW) {
    const int x0 = w * 4;
#pragma unroll
    for (int p = 0; p < 2; ++p) {
      sh.sAr[p * 256 + t] = vort[((size_t)g * 256 + x0 + 2 * p) * 256 + t];
      sh.sAi[p * 256 + t] = vort[((size_t)g * 256 + x0 + 2 * p + 1) * 256 + t];
    }
    fftB<2, false>(sh, t);
    if (t < 129) {
      int mI = (256 - t) & 255;
#pragma unroll
      for (int p = 0; p < 2; ++p) {
        float zr = sh.sAr[p * 256 + t],  zi = sh.sAi[p * 256 + t];
        float wr = sh.sAr[p * 256 + mI], wi2 = sh.sAi[p * 256 + mI];
        stg(&W1[(size_t)t * 256 + x0 + 2 * p],
            make_float2(0.5f * (zr + wr), 0.5f * (zi - wi2)));
        stg(&W1[(size_t)t * 256 + x0 + 2 * p + 1],
            make_float2(0.5f * (zi + wi2), 0.5f * (wr - zr)));
      }
    }
    __syncthreads();
  }
  GBAR();

  // ---- init: col FFT (W1 -> u) for ky<86, then prepare G ----
  for (int w = wi; w < 43; w += nW) {
    const int ky0 = w * 2;
#pragma unroll
    for (int f = 0; f < 2; ++f) {
      float2 v = ldc(&W1[(size_t)(ky0 + f) * 256 + t]);
      sh.sAr[f * 256 + t] = v.x; sh.sAi[f * 256 + t] = v.y;
    }
    fftB<2, false>(sh, t);
#pragma unroll
    for (int f = 0; f < 2; ++f)
      u[((size_t)g * 129 + ky0 + f) * 256 + t] =
        make_float2(sh.sAr[f * 256 + t], sh.sAi[f * 256 + t]);
  }
  for (int w = wi; w < 22; w += nW)
    spectral_item4_reg(sh, t, g, w * 4, NL1, u, h, G, rec, 0.f, 0.f, 0.f, false, -1);

  // ---- main loop: 90 steps x 5 RK stages ----
  for (int step = 1; step <= 90; ++step) {
    for (int k = 0; k < 5; ++k) {
      GBAR();
      for (int w = wi; w < 64; w += nW)
        real_item4_reg(sh, t, g, w * 4, G, NL1);
      GBAR();
      const int recIdx = (k == 4 && step % 30 == 0) ? (step / 30 - 1) : -1;
      for (int w = wi; w < 22; w += nW)
        spectral_item4_reg(sh, t, g, w * 4, NL1, u, h, G, rec,
                           c_beta[k], c_gdt[k], c_mu[k], true, recIdx);
    }
  }
  GBAR();

  // ---- final: inverse col FFT of records (258 rows, 2 per item) ----
  for (int w = wi; w < 129; w += nW) {
#pragma unroll
    for (int j = 0; j < 2; ++j) {
      int idx = w * 2 + j, r = idx / 86, ky = idx % 86;
      float2 v = ldc(&rec[(((size_t)r * 8 + g) * 129 + ky) * 256 + t]);
      sh.sAr[j * 256 + t] = v.x; sh.sAi[j * 256 + t] = v.y;
    }
    fftB<2, true>(sh, t);
#pragma unroll
    for (int j = 0; j < 2; ++j) {
      int idx = w * 2 + j, r = idx / 86, ky = idx % 86;
      stg(&G[(((size_t)r * 8 + g) * 129 + ky) * 256 + t],
          make_float2(sh.sAr[j * 256 + t], sh.sAi[j * 256 + t]));
    }
  }
  GBAR();

  // ---- final: paired hermitian inverse row FFT -> out (4 cols/item) ----
  const float NRM = 1.0f / 65536.0f;
  for (int w = wi; w < 192; w += nW) {
    const int r = w / 64, xh = w % 64, x0 = xh * 4;
    __syncthreads();
    for (int i = t; i < 344; i += 256) {
      int ky = i >> 2, xl = i & 3;
      float2 a = ldc(&G[(((size_t)r * 8 + g) * 129 + ky) * 256 + x0 + xl]);
      sh.t0r[ky * 5 + xl] = a.x; sh.t0i[ky * 5 + xl] = a.y;
    }
    __syncthreads();
    const bool lower = (t <= 128);
    const int  kk    = lower ? t : 256 - t;
#pragma unroll
    for (int f = 0; f < 2; ++f) {
      float ar = 0.f, ai = 0.f, br = 0.f, bi = 0.f;
      if (kk <= 85) {
        ar = sh.t0r[kk * 5 + 2 * f];     ai = sh.t0i[kk * 5 + 2 * f];
        br = sh.t0r[kk * 5 + 2 * f + 1]; bi = sh.t0i[kk * 5 + 2 * f + 1];
      }
      sh.sAr[f * 256 + t] = lower ? (ar - bi) : (ar + bi);
      sh.sAi[f * 256 + t] = lower ? (ai + br) : (br - ai);
    }
    fftB<2, true>(sh, t);
#pragma unroll
    for (int f = 0; f < 2; ++f) {
      out[((((size_t)r * 8 + g) * 256) + x0 + 2 * f) * 256 + t]     = sh.sAr[f * 256 + t] * NRM;
      out[((((size_t)r * 8 + g) * 256) + x0 + 2 * f + 1) * 256 + t] = sh.sAi[f * 256 + t] * NRM;
    }
    __syncthreads();
  }
#undef GBAR
}

// ---------------------------------------------------------------------------
extern "C" void kernel_launch(void* const* d_in, const int* in_sizes, int n_in,
                              void* d_out, int out_size, void* d_ws, size_t ws_size,
                              hipStream_t stream)
{
  const float* vort = (const float*)d_in[0];
  float* out = (float*)d_out;

  float2* base = (float2*)d_ws;
  float2* u    = base;                 // 8*129*256   = 264192
  float2* h    = u + 264192;           // 264192
  float2* G    = h + 264192;           // 4*8*129*256 = 1056768
  float2* NL1  = G + 1056768;          // 8*86*256    = 176128
  float2* rec  = NL1 + 176128;         // 3*8*129*256 = 792576
  Line*   bar  = (Line*)(rec + 792576);
  const int nLines = 1024 + 8 + 2048 + 64 + 16;   // 3160 lines

  hipMemsetAsync(bar, 0, (size_t)nLines * sizeof(Line), stream);

  int maxPerCU = 0;
  hipOccupancyMaxActiveBlocksPerMultiprocessor(&maxPerCU, k_persist, 256, 0);
  int NBg = maxPerCU * 256;            // 256 CUs on MI355X
  if (NBg <= 0)  NBg = 512;
  if (NBg > 512) NBg = 512;            // 64 blocks/XCD: all busy in real phase
  NBg &= ~63;
  if (NBg < 64)  NBg = 64;

  void* args[] = {(void*)&vort, (void*)&out, (void*)&u, (void*)&h,
                  (void*)&G, (void*)&NL1, (void*)&rec, (void*)&bar};
  hipError_t e = hipLaunchCooperativeKernel(k_persist, dim3(NBg), dim3(256),
                                            args, 0, stream);
  if (e != hipSuccess) {
    hipLaunchKernelGGL(k_persist, dim3(NBg), dim3(256), 0, stream,
                       vort, out, u, h, G, NL1, rec, bar);
  }
}